// Round 3
// baseline (16050.084 us; speedup 1.0000x reference)
//
#include <hip/hip_runtime.h>
#include <math.h>

// GPT-2 prefill: B=4 S=1024 E=768 H=12 L=12 F=3072 V=50257, fp32.
// Out layout: probs[4,50257] | K[12,4,1024,768] | V[12,4,1024,768]
// Round 3 submission == Round 0/1/2 kernel (all prior rounds were infra
// failures; need a correct fp32 baseline + counters before bf16/MFMA work).

constexpr int NB = 4;
constexpr int NS = 1024;
constexpr int NE = 768;
constexpr int NH = 12;
constexpr int NL = 12;
constexpr int NF = 3072;
constexpr int NDH = 64;
constexpr int NV = 50257;
constexpr int ROWS = NB * NS;          // 4096
constexpr float EPS = 1e-5f;

// ---------------- embedding ----------------
__global__ void embed_kernel(const int* __restrict__ ids,
                             const float* __restrict__ wte,
                             const float* __restrict__ wpe,
                             float* __restrict__ x) {
    int row = blockIdx.x;              // 0..ROWS-1
    int s = row & (NS - 1);
    int tok = ids[row];
    const float* src = wte + (size_t)tok * NE;
    const float* pp  = wpe + (size_t)s * NE;
    float* dst = x + (size_t)row * NE;
    for (int e = threadIdx.x; e < NE; e += blockDim.x)
        dst[e] = src[e] + pp[e];
}

// ---------------- layernorm (row of 768, block=256) ----------------
__global__ __launch_bounds__(256) void ln_kernel(const float* __restrict__ x,
                                                 const float* __restrict__ w,
                                                 const float* __restrict__ b,
                                                 float* __restrict__ out) {
    __shared__ float red[256];
    int row = blockIdx.x;
    int t = threadIdx.x;
    const float* xr = x + (size_t)row * NE;
    float a0 = xr[t], a1 = xr[t + 256], a2 = xr[t + 512];
    red[t] = a0 + a1 + a2;
    __syncthreads();
    for (int off = 128; off; off >>= 1) {
        if (t < off) red[t] += red[t + off];
        __syncthreads();
    }
    float mu = red[0] * (1.0f / NE);
    __syncthreads();
    float d0 = a0 - mu, d1 = a1 - mu, d2 = a2 - mu;
    red[t] = d0 * d0 + d1 * d1 + d2 * d2;
    __syncthreads();
    for (int off = 128; off; off >>= 1) {
        if (t < off) red[t] += red[t + off];
        __syncthreads();
    }
    float rstd = rsqrtf(red[0] * (1.0f / NE) + EPS);
    float* orow = out + (size_t)row * NE;
    orow[t]       = d0 * rstd * w[t]       + b[t];
    orow[t + 256] = d1 * rstd * w[t + 256] + b[t + 256];
    orow[t + 512] = d2 * rstd * w[t + 512] + b[t + 512];
}

// ---------------- fp32 GEMM: C[M,N] = A[M,K] @ W[K,N] + bias (+gelu)(+res) ----
// 128x128 tile, K-step 16, 256 threads, 8x8 microtile.
template <int ACT, bool RES>
__global__ __launch_bounds__(256) void gemm_kernel(const float* __restrict__ A,
                                                   const float* __restrict__ Wm,
                                                   const float* __restrict__ bias,
                                                   const float* __restrict__ res,
                                                   float* __restrict__ C,
                                                   int M, int N, int K) {
    __shared__ float As[16][132];   // [k][row], padded
    __shared__ float Bs[16][132];   // [k][col], padded
    int tid = threadIdx.x;
    int tx = tid & 15, ty = tid >> 4;
    int n0 = blockIdx.x * 128, m0 = blockIdx.y * 128;

    float acc[8][8] = {};

    for (int k0 = 0; k0 < K; k0 += 16) {
        // A tile: 128 rows x 16 k (512 float4, 2/thread), store transposed
        #pragma unroll
        for (int r = 0; r < 2; ++r) {
            int i = tid + r * 256;          // float4 index 0..511
            int row = i >> 2;
            int c4 = (i & 3) * 4;
            float4 v = *reinterpret_cast<const float4*>(A + (size_t)(m0 + row) * K + k0 + c4);
            As[c4 + 0][row] = v.x; As[c4 + 1][row] = v.y;
            As[c4 + 2][row] = v.z; As[c4 + 3][row] = v.w;
        }
        // B tile: 16 k x 128 cols (512 float4, 2/thread)
        #pragma unroll
        for (int r = 0; r < 2; ++r) {
            int i = tid + r * 256;
            int kk = i >> 5;
            int c4 = (i & 31) * 4;
            *reinterpret_cast<float4*>(&Bs[kk][c4]) =
                *reinterpret_cast<const float4*>(Wm + (size_t)(k0 + kk) * N + n0 + c4);
        }
        __syncthreads();
        #pragma unroll
        for (int kk = 0; kk < 16; ++kk) {
            float a[8], bv[8];
            *reinterpret_cast<float4*>(&a[0])  = *reinterpret_cast<float4*>(&As[kk][ty * 8]);
            *reinterpret_cast<float4*>(&a[4])  = *reinterpret_cast<float4*>(&As[kk][ty * 8 + 4]);
            *reinterpret_cast<float4*>(&bv[0]) = *reinterpret_cast<float4*>(&Bs[kk][tx * 8]);
            *reinterpret_cast<float4*>(&bv[4]) = *reinterpret_cast<float4*>(&Bs[kk][tx * 8 + 4]);
            #pragma unroll
            for (int i = 0; i < 8; ++i)
                #pragma unroll
                for (int j = 0; j < 8; ++j)
                    acc[i][j] = fmaf(a[i], bv[j], acc[i][j]);
        }
        __syncthreads();
    }

    #pragma unroll
    for (int i = 0; i < 8; ++i) {
        int row = m0 + ty * 8 + i;
        #pragma unroll
        for (int j = 0; j < 8; ++j) {
            int col = n0 + tx * 8 + j;
            float v = acc[i][j] + bias[col];
            if (ACT == 1) v = 0.5f * v * (1.0f + erff(v * 0.70710678118654752f));
            if (RES) v += res[(size_t)row * N + col];
            acc[i][j] = v;
        }
        float4* dst = reinterpret_cast<float4*>(C + (size_t)row * N + n0 + tx * 8);
        dst[0] = *reinterpret_cast<float4*>(&acc[i][0]);
        dst[1] = *reinterpret_cast<float4*>(&acc[i][4]);
    }
}

// ---------------- copy K/V slices of qkv into output caches ----------------
__global__ void copykv_kernel(const float* __restrict__ qkv,
                              float* __restrict__ Kc, float* __restrict__ Vc) {
    int row = blockIdx.x;
    const float* src = qkv + (size_t)row * (3 * NE);
    float* kd = Kc + (size_t)row * NE;
    float* vd = Vc + (size_t)row * NE;
    for (int e = threadIdx.x; e < NE; e += blockDim.x) {
        kd[e] = src[NE + e];
        vd[e] = src[2 * NE + e];
    }
}

// ---------------- flash attention (fp32), QB=KB=64, 256 thr, 4x4 microtile --
__global__ __launch_bounds__(256) void attn_kernel(const float* __restrict__ qkv,
                                                   float* __restrict__ ctx) {
    constexpr int QB = 64, KB = 64;
    __shared__ float Qs[QB][NDH + 1];
    __shared__ float Ks[KB][NDH + 1];
    __shared__ float Vs[KB][NDH + 1];
    __shared__ float Ps[QB][KB + 1];

    int tid = threadIdx.x;
    int tx = tid & 15, ty = tid >> 4;
    constexpr int nqb = NS / QB;                 // 16
    int qb = blockIdx.x % nqb;
    int h  = (blockIdx.x / nqb) % NH;
    int b  = blockIdx.x / (nqb * NH);
    const size_t base = (size_t)b * NS * (3 * NE);

    // load Q tile (QB x 64)
    for (int i = tid; i < QB * NDH / 4; i += 256) {
        int row = i >> 4;
        int c4 = (i & 15) * 4;
        float4 v = *reinterpret_cast<const float4*>(
            qkv + base + (size_t)(qb * QB + row) * (3 * NE) + h * NDH + c4);
        Qs[row][c4] = v.x; Qs[row][c4 + 1] = v.y; Qs[row][c4 + 2] = v.z; Qs[row][c4 + 3] = v.w;
    }

    float m[4], l[4], acc[4][4];
    #pragma unroll
    for (int i = 0; i < 4; ++i) {
        m[i] = -1e30f; l[i] = 0.f;
        #pragma unroll
        for (int j = 0; j < 4; ++j) acc[i][j] = 0.f;
    }

    const float scale = 0.125f;                  // 1/sqrt(64)

    for (int t = 0; t <= qb; ++t) {
        __syncthreads();                         // prev tile fully consumed
        for (int i = tid; i < KB * NDH / 4; i += 256) {
            int row = i >> 4;
            int c4 = (i & 15) * 4;
            size_t g = base + (size_t)(t * KB + row) * (3 * NE) + NE + h * NDH + c4;
            float4 kv = *reinterpret_cast<const float4*>(qkv + g);
            Ks[row][c4] = kv.x; Ks[row][c4 + 1] = kv.y; Ks[row][c4 + 2] = kv.z; Ks[row][c4 + 3] = kv.w;
            float4 vv = *reinterpret_cast<const float4*>(qkv + g + NE);
            Vs[row][c4] = vv.x; Vs[row][c4 + 1] = vv.y; Vs[row][c4 + 2] = vv.z; Vs[row][c4 + 3] = vv.w;
        }
        __syncthreads();

        // scores: 4q x 4k per thread
        float sc[4][4] = {};
        for (int d = 0; d < NDH; ++d) {
            float a[4], kvv[4];
            #pragma unroll
            for (int i = 0; i < 4; ++i) a[i] = Qs[ty * 4 + i][d];
            #pragma unroll
            for (int j = 0; j < 4; ++j) kvv[j] = Ks[tx * 4 + j][d];
            #pragma unroll
            for (int i = 0; i < 4; ++i)
                #pragma unroll
                for (int j = 0; j < 4; ++j)
                    sc[i][j] = fmaf(a[i], kvv[j], sc[i][j]);
        }

        bool diag = (t == qb);
        #pragma unroll
        for (int i = 0; i < 4; ++i) {
            int qg = qb * QB + ty * 4 + i;
            float rowmax = -1e30f;
            #pragma unroll
            for (int j = 0; j < 4; ++j) {
                float v = sc[i][j] * scale;
                if (diag) {
                    int kg = t * KB + tx * 4 + j;
                    if (kg > qg) v = -1e30f;
                }
                sc[i][j] = v;
                rowmax = fmaxf(rowmax, v);
            }
            #pragma unroll
            for (int off = 8; off; off >>= 1)
                rowmax = fmaxf(rowmax, __shfl_xor(rowmax, off, 16));
            float mnew = fmaxf(m[i], rowmax);
            float corr = expf(m[i] - mnew);
            float rsum = 0.f;
            #pragma unroll
            for (int j = 0; j < 4; ++j) {
                float p = expf(sc[i][j] - mnew);
                sc[i][j] = p;
                rsum += p;
            }
            #pragma unroll
            for (int off = 8; off; off >>= 1)
                rsum += __shfl_xor(rsum, off, 16);
            l[i] = l[i] * corr + rsum;
            m[i] = mnew;
            #pragma unroll
            for (int j = 0; j < 4; ++j) acc[i][j] *= corr;
            #pragma unroll
            for (int j = 0; j < 4; ++j) Ps[ty * 4 + i][tx * 4 + j] = sc[i][j];
        }
        __syncthreads();

        // acc += P @ V   (thread owns 4q x 4d, d = tx*4+j)
        for (int kk = 0; kk < KB; ++kk) {
            float p4[4], v4[4];
            #pragma unroll
            for (int i = 0; i < 4; ++i) p4[i] = Ps[ty * 4 + i][kk];
            #pragma unroll
            for (int j = 0; j < 4; ++j) v4[j] = Vs[kk][tx * 4 + j];
            #pragma unroll
            for (int i = 0; i < 4; ++i)
                #pragma unroll
                for (int j = 0; j < 4; ++j)
                    acc[i][j] = fmaf(p4[i], v4[j], acc[i][j]);
        }
    }

    #pragma unroll
    for (int i = 0; i < 4; ++i) {
        int qg = qb * QB + ty * 4 + i;
        float inv = 1.0f / l[i];
        float o[4];
        #pragma unroll
        for (int j = 0; j < 4; ++j) o[j] = acc[i][j] * inv;
        *reinterpret_cast<float4*>(ctx + ((size_t)b * NS + qg) * NE + h * NDH + tx * 4) =
            *reinterpret_cast<float4*>(&o[0]);
    }
}

// ---------------- last valid position per batch row ----------------
__global__ void lastpos_kernel(const int* __restrict__ mask, int* __restrict__ last) {
    int b = threadIdx.x;
    if (b < NB) {
        int mx = mask[(size_t)b * NS];
        for (int j = 1; j < NS; ++j) mx = max(mx, mask[(size_t)b * NS + j]);
        int pos = 0;
        for (int j = NS - 1; j >= 0; --j) {
            if (mask[(size_t)b * NS + j] == mx) { pos = j; break; }
        }
        last[b] = pos;
    }
}

// ---------------- final LN on the gathered last rows ----------------
__global__ __launch_bounds__(256) void final_ln_gather(const float* __restrict__ x,
                                                       const int* __restrict__ last,
                                                       const float* __restrict__ w,
                                                       const float* __restrict__ b,
                                                       float* __restrict__ out) {
    __shared__ float red[256];
    int bb = blockIdx.x;
    int t = threadIdx.x;
    const float* xr = x + ((size_t)bb * NS + last[bb]) * NE;
    float a0 = xr[t], a1 = xr[t + 256], a2 = xr[t + 512];
    red[t] = a0 + a1 + a2;
    __syncthreads();
    for (int off = 128; off; off >>= 1) {
        if (t < off) red[t] += red[t + off];
        __syncthreads();
    }
    float mu = red[0] * (1.0f / NE);
    __syncthreads();
    float d0 = a0 - mu, d1 = a1 - mu, d2 = a2 - mu;
    red[t] = d0 * d0 + d1 * d1 + d2 * d2;
    __syncthreads();
    for (int off = 128; off; off >>= 1) {
        if (t < off) red[t] += red[t + off];
        __syncthreads();
    }
    float rstd = rsqrtf(red[0] * (1.0f / NE) + EPS);
    float* orow = out + (size_t)bb * NE;
    orow[t]       = d0 * rstd * w[t]       + b[t];
    orow[t + 256] = d1 * rstd * w[t + 256] + b[t + 256];
    orow[t + 512] = d2 * rstd * w[t + 512] + b[t + 512];
}

// ---------------- lm_head: logits[b,v] = dot(ls[b], wte[v]) ----------------
__global__ __launch_bounds__(256) void lmhead_kernel(const float* __restrict__ ls,
                                                     const float* __restrict__ wte,
                                                     float* __restrict__ logits) {
    __shared__ float q[NB][NE];
    __shared__ float red[NB][256];
    int tid = threadIdx.x;
    for (int i = tid; i < NB * NE; i += 256) q[i / NE][i % NE] = ls[i];
    __syncthreads();
    int v = blockIdx.x;
    const float* wr = wte + (size_t)v * NE;
    float acc[NB] = {};
    for (int e = tid; e < NE; e += 256) {
        float wv = wr[e];
        #pragma unroll
        for (int b = 0; b < NB; ++b) acc[b] = fmaf(wv, q[b][e], acc[b]);
    }
    #pragma unroll
    for (int b = 0; b < NB; ++b) red[b][tid] = acc[b];
    __syncthreads();
    for (int off = 128; off; off >>= 1) {
        if (tid < off) {
            #pragma unroll
            for (int b = 0; b < NB; ++b) red[b][tid] += red[b][tid + off];
        }
        __syncthreads();
    }
    if (tid < NB) logits[(size_t)tid * NV + v] = red[tid][0];
}

// ---------------- softmax over V per batch row ----------------
__global__ __launch_bounds__(256) void softmax_kernel(const float* __restrict__ logits,
                                                      float* __restrict__ probs) {
    __shared__ float red[256];
    int b = blockIdx.x;
    int tid = threadIdx.x;
    const float* lr = logits + (size_t)b * NV;
    float mx = -1e30f;
    for (int v = tid; v < NV; v += 256) mx = fmaxf(mx, lr[v]);
    red[tid] = mx;
    __syncthreads();
    for (int off = 128; off; off >>= 1) {
        if (tid < off) red[tid] = fmaxf(red[tid], red[tid + off]);
        __syncthreads();
    }
    mx = red[0];
    __syncthreads();
    float sum = 0.f;
    for (int v = tid; v < NV; v += 256) sum += expf(lr[v] - mx);
    red[tid] = sum;
    __syncthreads();
    for (int off = 128; off; off >>= 1) {
        if (tid < off) red[tid] += red[tid + off];
        __syncthreads();
    }
    float inv = 1.0f / red[0];
    for (int v = tid; v < NV; v += 256) probs[(size_t)b * NV + v] = expf(lr[v] - mx) * inv;
}

// ---------------- host orchestration ----------------
extern "C" void kernel_launch(void* const* d_in, const int* in_sizes, int n_in,
                              void* d_out, int out_size, void* d_ws, size_t ws_size,
                              hipStream_t stream) {
    const int*   input_ids = (const int*)d_in[0];
    const int*   attn_mask = (const int*)d_in[1];
    const float* wte    = (const float*)d_in[2];
    const float* wpe    = (const float*)d_in[3];
    const float* ln1_w  = (const float*)d_in[4];
    const float* ln1_b  = (const float*)d_in[5];
    const float* qkv_w  = (const float*)d_in[6];
    const float* qkv_b  = (const float*)d_in[7];
    const float* proj_w = (const float*)d_in[8];
    const float* proj_b = (const float*)d_in[9];
    // d_in[10] = attn_bias (tril ones, additive) — uniform +1 on valid entries,
    // softmax-invariant → intentionally unused.
    const float* ln2_w  = (const float*)d_in[11];
    const float* ln2_b  = (const float*)d_in[12];
    const float* fc_w   = (const float*)d_in[13];
    const float* fc_b   = (const float*)d_in[14];
    const float* p2_w   = (const float*)d_in[15];
    const float* p2_b   = (const float*)d_in[16];
    const float* lnf_w  = (const float*)d_in[17];
    const float* lnf_b  = (const float*)d_in[18];

    // workspace layout (floats)
    float* x    = (float*)d_ws;                       // ROWS*NE
    float* hn   = x   + (size_t)ROWS * NE;            // ROWS*NE
    float* ctx  = hn  + (size_t)ROWS * NE;            // ROWS*NE
    float* big  = ctx + (size_t)ROWS * NE;            // ROWS*NF (qkv shares: ROWS*3E < ROWS*NF)
    float* logits = big + (size_t)ROWS * NF;          // NB*NV
    int*   last = (int*)(logits + (size_t)NB * NV);   // NB

    // output layout
    float* probs = (float*)d_out;
    float* Kc = probs + (size_t)NB * NV;
    float* Vc = Kc + (size_t)NL * ROWS * NE;

    embed_kernel<<<ROWS, 256, 0, stream>>>(input_ids, wte, wpe, x);

    for (int l = 0; l < NL; ++l) {
        ln_kernel<<<ROWS, 256, 0, stream>>>(x, ln1_w + (size_t)l * NE, ln1_b + (size_t)l * NE, hn);

        gemm_kernel<0, false><<<dim3(3 * NE / 128, ROWS / 128), 256, 0, stream>>>(
            hn, qkv_w + (size_t)l * NE * 3 * NE, qkv_b + (size_t)l * 3 * NE, nullptr, big,
            ROWS, 3 * NE, NE);

        copykv_kernel<<<ROWS, 256, 0, stream>>>(big,
            Kc + (size_t)l * ROWS * NE, Vc + (size_t)l * ROWS * NE);

        attn_kernel<<<NB * NH * (NS / 64), 256, 0, stream>>>(big, ctx);

        gemm_kernel<0, true><<<dim3(NE / 128, ROWS / 128), 256, 0, stream>>>(
            ctx, proj_w + (size_t)l * NE * NE, proj_b + (size_t)l * NE, x, x,
            ROWS, NE, NE);

        ln_kernel<<<ROWS, 256, 0, stream>>>(x, ln2_w + (size_t)l * NE, ln2_b + (size_t)l * NE, hn);

        gemm_kernel<1, false><<<dim3(NF / 128, ROWS / 128), 256, 0, stream>>>(
            hn, fc_w + (size_t)l * NE * NF, fc_b + (size_t)l * NF, nullptr, big,
            ROWS, NF, NE);

        gemm_kernel<0, true><<<dim3(NE / 128, ROWS / 128), 256, 0, stream>>>(
            big, p2_w + (size_t)l * NF * NE, p2_b + (size_t)l * NE, x, x,
            ROWS, NE, NF);
    }

    lastpos_kernel<<<1, 64, 0, stream>>>(attn_mask, last);
    final_ln_gather<<<NB, 256, 0, stream>>>(x, last, lnf_w, lnf_b, hn);  // hn[0:NB*NE] = last_states
    lmhead_kernel<<<NV, 256, 0, stream>>>(hn, wte, logits);
    softmax_kernel<<<NB, 256, 0, stream>>>(logits, probs);
}